// Round 1
// baseline (85.674 us; speedup 1.0000x reference)
//
#include <hip/hip_runtime.h>

// VocabEmbeddingWithLoRA: out[b,s,d] = W[x[b,s], d] + sum_r A[r, x[b,s]] * B[d, r]
// VOCAB=128000, D=2048, RANK=16, tokens = 4*4096 = 16384. All fp32, x int32.

#define VOCAB   128000
#define DMODEL  2048
#define RANK    16
#define TPB     32            // tokens per block
#define THREADS 512           // = DMODEL/4 float4 lanes

__device__ __forceinline__ float dot16(const float4* __restrict__ b,
                                       const float4& c0, const float4& c1,
                                       const float4& c2, const float4& c3) {
    float s;
    s  = b[0].x * c0.x + b[0].y * c0.y + b[0].z * c0.z + b[0].w * c0.w;
    s += b[1].x * c1.x + b[1].y * c1.y + b[1].z * c1.z + b[1].w * c1.w;
    s += b[2].x * c2.x + b[2].y * c2.y + b[2].z * c2.z + b[2].w * c2.w;
    s += b[3].x * c3.x + b[3].y * c3.y + b[3].z * c3.z + b[3].w * c3.w;
    return s;
}

__global__ __launch_bounds__(THREADS)
void embed_lora_kernel(const int* __restrict__ x,
                       const float* __restrict__ W,
                       const float* __restrict__ A,
                       const float* __restrict__ Bm,
                       float* __restrict__ out) {
    __shared__ int   toks[TPB];
    __shared__ float4 code4[TPB][RANK / 4];   // per-token LoRA code, 16 floats each

    const int tid   = threadIdx.x;
    const int tbase = blockIdx.x * TPB;

    if (tid < TPB) toks[tid] = x[tbase + tid];
    __syncthreads();

    // Gather per-token codes: 512 threads = 32 tokens x 16 ranks.
    {
        const int j = tid >> 4;
        const int r = tid & 15;
        ((float*)&code4[j][0])[r] = A[(size_t)r * VOCAB + (size_t)toks[j]];
    }

    // Register-resident lora_B fragment: this thread's 4 output dims x 16 ranks.
    const int d0 = tid * 4;
    float4 B0[4], B1[4], B2[4], B3[4];
    {
        const float4* Bp = (const float4*)(Bm + (size_t)d0 * RANK);
        #pragma unroll
        for (int q = 0; q < 4; ++q) {
            B0[q] = Bp[q];
            B1[q] = Bp[4 + q];
            B2[q] = Bp[8 + q];
            B3[q] = Bp[12 + q];
        }
    }
    __syncthreads();

    #pragma unroll 4
    for (int j = 0; j < TPB; ++j) {
        const float4 c0 = code4[j][0];
        const float4 c1 = code4[j][1];
        const float4 c2 = code4[j][2];
        const float4 c3 = code4[j][3];

        const size_t wrow = (size_t)toks[j] * DMODEL;
        const float4 w = ((const float4*)(W + wrow))[tid];

        float4 o;
        o.x = w.x + dot16(B0, c0, c1, c2, c3);
        o.y = w.y + dot16(B1, c0, c1, c2, c3);
        o.z = w.z + dot16(B2, c0, c1, c2, c3);
        o.w = w.w + dot16(B3, c0, c1, c2, c3);

        ((float4*)out)[(size_t)(tbase + j) * (DMODEL / 4) + tid] = o;
    }
}

extern "C" void kernel_launch(void* const* d_in, const int* in_sizes, int n_in,
                              void* d_out, int out_size, void* d_ws, size_t ws_size,
                              hipStream_t stream) {
    const int*   x  = (const int*)d_in[0];
    const float* W  = (const float*)d_in[1];
    const float* A  = (const float*)d_in[2];
    const float* Bm = (const float*)d_in[3];
    float*       o  = (float*)d_out;

    const int n_tokens = in_sizes[0];            // 16384
    const int n_blocks = n_tokens / TPB;         // 512

    embed_lora_kernel<<<n_blocks, THREADS, 0, stream>>>(x, W, A, Bm, o);
}

// Round 3
// 64.701 us; speedup vs baseline: 1.3242x; 1.3242x over previous
//
#include <hip/hip_runtime.h>

// VocabEmbeddingWithLoRA: out[b,s,d] = W[x[b,s], d] + sum_r A[r, x[b,s]] * B[d, r]
// VOCAB=128000, D=2048, RANK=16, tokens = 4*4096 = 16384. All fp32, x int32.
//
// Structure: 512 threads = 512 float4 lanes covering D=2048. 32 tokens/block,
// 512 blocks (all co-resident at 4 waves/SIMD). lora_B fragment (4 dims x 16
// ranks = 64 floats) lives in registers; per-token codes in LDS (broadcast
// reads). Token ids read via the SCALAR path (uniform address -> s_load),
// W row loads explicitly prefetched 6 deep, nontemporal for single-use data.
//
// NOTE: __builtin_nontemporal_* requires a clang vector type, not HIP's
// float4 class -> use ext_vector_type(4) alias fx4.

#define VOCAB   128000
#define DMODEL  2048
#define RANK    16
#define TPB     32            // tokens per block
#define THREADS 512           // = DMODEL/4 float4 lanes
#define PF      6             // prefetch depth (W rows in flight per wave)

typedef float fx4 __attribute__((ext_vector_type(4)));

__device__ __forceinline__ float dot16(const fx4* __restrict__ b,
                                       const fx4& c0, const fx4& c1,
                                       const fx4& c2, const fx4& c3) {
    float s;
    s  = b[0].x * c0.x + b[0].y * c0.y + b[0].z * c0.z + b[0].w * c0.w;
    s += b[1].x * c1.x + b[1].y * c1.y + b[1].z * c1.z + b[1].w * c1.w;
    s += b[2].x * c2.x + b[2].y * c2.y + b[2].z * c2.z + b[2].w * c2.w;
    s += b[3].x * c3.x + b[3].y * c3.y + b[3].z * c3.z + b[3].w * c3.w;
    return s;
}

__global__ __launch_bounds__(THREADS, 4)
void embed_lora_kernel(const int* __restrict__ x,
                       const float* __restrict__ W,
                       const float* __restrict__ A,
                       const float* __restrict__ Bm,
                       float* __restrict__ out) {
    __shared__ fx4 code4[TPB][RANK / 4];   // per-token LoRA code, 16 floats

    const int tid   = threadIdx.x;
    const int tbase = blockIdx.x * TPB;

    // Gather per-token codes: 512 threads = 32 tokens x 16 ranks (per-lane path).
    {
        const int j   = tid >> 4;
        const int r   = tid & 15;
        const int tok = x[tbase + j];
        ((float*)&code4[j][0])[r] = A[(size_t)r * VOCAB + (size_t)tok];
    }

    // Register-resident lora_B fragment: this thread's 4 output dims x 16 ranks.
    const int d0 = tid * 4;
    fx4 B0[4], B1[4], B2[4], B3[4];
    {
        const fx4* Bp = (const fx4*)(Bm + (size_t)d0 * RANK);
        #pragma unroll
        for (int q = 0; q < 4; ++q) {
            B0[q] = Bp[q];
            B1[q] = Bp[4 + q];
            B2[q] = Bp[8 + q];
            B3[q] = Bp[12 + q];
        }
    }
    __syncthreads();

    // Explicit software pipeline on the W-row gather. Token ids are read with
    // compile-time j and block-uniform tbase -> scalar loads (s_load), so the
    // global load is saddr + small voffset with no per-lane 64-bit math.
    fx4 wbuf[PF];
    #pragma unroll
    for (int p = 0; p < PF; ++p) {
        const size_t row = (size_t)x[tbase + p] * DMODEL;   // uniform -> SGPR
        wbuf[p] = __builtin_nontemporal_load(&((const fx4*)(W + row))[tid]);
    }

    #pragma unroll
    for (int j = 0; j < TPB; ++j) {
        const fx4 w = wbuf[j % PF];                          // static index (full unroll)
        if (j + PF < TPB) {
            const size_t row = (size_t)x[tbase + j + PF] * DMODEL;
            wbuf[j % PF] = __builtin_nontemporal_load(&((const fx4*)(W + row))[tid]);
        }

        const fx4 c0 = code4[j][0];
        const fx4 c1 = code4[j][1];
        const fx4 c2 = code4[j][2];
        const fx4 c3 = code4[j][3];

        fx4 o;
        o.x = w.x + dot16(B0, c0, c1, c2, c3);
        o.y = w.y + dot16(B1, c0, c1, c2, c3);
        o.z = w.z + dot16(B2, c0, c1, c2, c3);
        o.w = w.w + dot16(B3, c0, c1, c2, c3);

        __builtin_nontemporal_store(o, &((fx4*)out)[(size_t)(tbase + j) * (DMODEL / 4) + tid]);
    }
}

extern "C" void kernel_launch(void* const* d_in, const int* in_sizes, int n_in,
                              void* d_out, int out_size, void* d_ws, size_t ws_size,
                              hipStream_t stream) {
    const int*   x  = (const int*)d_in[0];
    const float* W  = (const float*)d_in[1];
    const float* A  = (const float*)d_in[2];
    const float* Bm = (const float*)d_in[3];
    float*       o  = (float*)d_out;

    const int n_tokens = in_sizes[0];            // 16384
    const int n_blocks = n_tokens / TPB;         // 512

    embed_lora_kernel<<<n_blocks, THREADS, 0, stream>>>(x, W, A, Bm, o);
}

// Round 4
// 62.081 us; speedup vs baseline: 1.3800x; 1.0422x over previous
//
#include <hip/hip_runtime.h>

// VocabEmbeddingWithLoRA: out[b,s,d] = W[x[b,s], d] + sum_r A[r, x[b,s]] * B[d, r]
// VOCAB=128000, D=2048, RANK=16, tokens = 4*4096 = 16384. All fp32, x int32.
//
// R4 structure: 1024 threads/block, each thread owns 2 output dims x 16 ranks
// (B-fragment = 32 VGPR), TPB=32 tokens/block, grid 512. Target <=64 VGPR so
// occupancy doubles to 8 waves/SIMD (32 waves/CU) -> more independent wave
// streams to absorb random-row HBM latency (in-order vmcnt HOL blocking).
// W prologue (PF=4 deep, 8B/lane fx2 loads) issued BEFORE __syncthreads --
// it depends only on scalar x reads, not on the LDS code gather.

#define VOCAB   128000
#define DMODEL  2048
#define RANK    16
#define TPB     32            // tokens per block
#define THREADS 1024          // = DMODEL/2 lanes, 2 dims per thread
#define PF      4             // prefetch depth (W row-fragments in flight)

typedef float fx4 __attribute__((ext_vector_type(4)));
typedef float fx2 __attribute__((ext_vector_type(2)));

__global__ __launch_bounds__(THREADS, 8)
void embed_lora_kernel(const int* __restrict__ x,
                       const float* __restrict__ W,
                       const float* __restrict__ A,
                       const float* __restrict__ Bm,
                       float* __restrict__ out) {
    __shared__ fx4 code4[TPB][RANK / 4];   // per-token LoRA code, 16 floats

    const int tid   = threadIdx.x;
    const int tbase = blockIdx.x * TPB;

    // Gather per-token codes: 512 of 1024 threads = 32 tokens x 16 ranks.
    if (tid < 512) {
        const int j   = tid >> 4;
        const int r   = tid & 15;
        const int tok = x[tbase + j];
        ((float*)&code4[j][0])[r] = A[(size_t)r * VOCAB + (size_t)tok];
    }

    // Register-resident lora_B fragment: 2 dims x 16 ranks = 32 VGPR.
    const int d0 = tid * 2;
    fx4 B0[4], B1[4];
    {
        const fx4* Bp = (const fx4*)(Bm + (size_t)d0 * RANK);
        #pragma unroll
        for (int q = 0; q < 4; ++q) {
            B0[q] = Bp[q];       // dim d0,   ranks 0..15
            B1[q] = Bp[4 + q];   // dim d0+1, ranks 0..15
        }
    }

    // W prologue BEFORE the barrier: depends only on uniform x reads.
    fx2 wbuf[PF];
    #pragma unroll
    for (int p = 0; p < PF; ++p) {
        const size_t row = (size_t)x[tbase + p] * DMODEL;   // uniform -> SGPR
        wbuf[p] = __builtin_nontemporal_load(&((const fx2*)(W + row))[tid]);
    }

    __syncthreads();

    #pragma unroll
    for (int j = 0; j < TPB; ++j) {
        const fx2 w = wbuf[j % PF];                          // static index (full unroll)
        if (j + PF < TPB) {
            const size_t row = (size_t)x[tbase + j + PF] * DMODEL;
            wbuf[j % PF] = __builtin_nontemporal_load(&((const fx2*)(W + row))[tid]);
        }

        const fx4 c0 = code4[j][0];
        const fx4 c1 = code4[j][1];
        const fx4 c2 = code4[j][2];
        const fx4 c3 = code4[j][3];

        float s0, s1;
        s0  = B0[0].x * c0.x + B0[0].y * c0.y + B0[0].z * c0.z + B0[0].w * c0.w;
        s0 += B0[1].x * c1.x + B0[1].y * c1.y + B0[1].z * c1.z + B0[1].w * c1.w;
        s0 += B0[2].x * c2.x + B0[2].y * c2.y + B0[2].z * c2.z + B0[2].w * c2.w;
        s0 += B0[3].x * c3.x + B0[3].y * c3.y + B0[3].z * c3.z + B0[3].w * c3.w;

        s1  = B1[0].x * c0.x + B1[0].y * c0.y + B1[0].z * c0.z + B1[0].w * c0.w;
        s1 += B1[1].x * c1.x + B1[1].y * c1.y + B1[1].z * c1.z + B1[1].w * c1.w;
        s1 += B1[2].x * c2.x + B1[2].y * c2.y + B1[2].z * c2.z + B1[2].w * c2.w;
        s1 += B1[3].x * c3.x + B1[3].y * c3.y + B1[3].z * c3.z + B1[3].w * c3.w;

        fx2 o;
        o.x = w.x + s0;
        o.y = w.y + s1;

        __builtin_nontemporal_store(o, &((fx2*)out)[(size_t)(tbase + j) * (DMODEL / 2) + tid]);
    }
}

extern "C" void kernel_launch(void* const* d_in, const int* in_sizes, int n_in,
                              void* d_out, int out_size, void* d_ws, size_t ws_size,
                              hipStream_t stream) {
    const int*   x  = (const int*)d_in[0];
    const float* W  = (const float*)d_in[1];
    const float* A  = (const float*)d_in[2];
    const float* Bm = (const float*)d_in[3];
    float*       o  = (float*)d_out;

    const int n_tokens = in_sizes[0];            // 16384
    const int n_blocks = n_tokens / TPB;         // 512

    embed_lora_kernel<<<n_blocks, THREADS, 0, stream>>>(x, W, A, Bm, o);
}